// Round 1
// baseline (1320.616 us; speedup 1.0000x reference)
//
#include <hip/hip_runtime.h>
#include <cstdint>
#include <cstddef>

// ---------------------------------------------------------------------------
// DeeperGCN forward on MI355X. Round 1: fp32 correctness baseline.
// N=10000 nodes, E=160000 edges, H=128, L=14 layers, G=64 graphs.
// ---------------------------------------------------------------------------

__device__ inline float wave_sum(float v) {
#pragma unroll
    for (int off = 32; off > 0; off >>= 1) v += __shfl_xor(v, off, 64);
    return v;
}

// ---------------- CSR construction ----------------
__global__ void hist_kernel(const int* __restrict__ dst, int* __restrict__ deg, int E) {
    int e = blockIdx.x * blockDim.x + threadIdx.x;
    if (e < E) atomicAdd(&deg[dst[e]], 1);
}

// single-workgroup exclusive scan of deg[0..N) -> offs[0..N], copy to cursor
__global__ __launch_bounds__(1024) void scan_kernel(const int* __restrict__ deg,
                                                    int* __restrict__ offs,
                                                    int* __restrict__ cursor, int N) {
    __shared__ int part[1024];
    int tid = threadIdx.x;
    int CH = (N + 1023) / 1024;
    int base = tid * CH;
    int s = 0;
    for (int i = 0; i < CH; i++) {
        int idx = base + i;
        if (idx < N) s += deg[idx];
    }
    part[tid] = s;
    __syncthreads();
    for (int off = 1; off < 1024; off <<= 1) {
        int v = (tid >= off) ? part[tid - off] : 0;
        __syncthreads();
        part[tid] += v;
        __syncthreads();
    }
    int run = (tid == 0) ? 0 : part[tid - 1];
    for (int i = 0; i < CH; i++) {
        int idx = base + i;
        if (idx < N) {
            offs[idx] = run;
            cursor[idx] = run;
            run += deg[idx];
        }
    }
    if (tid == 1023) offs[N] = part[1023];
}

__global__ void scatter_kernel(const int* __restrict__ src, const int* __restrict__ dst,
                               int* __restrict__ cursor, int* __restrict__ esrc, int E) {
    int e = blockIdx.x * blockDim.x + threadIdx.x;
    if (e < E) {
        int d = dst[e];
        int pos = atomicAdd(&cursor[d], 1);
        esrc[pos] = src[e];
    }
}

// ---------------- generic fp32 GEMM: C = A[M,K] @ B[K,Nc] (+bias) (+Cin) ----
template <bool BIAS, bool ADDC>
__global__ __launch_bounds__(256) void gemm_f32(const float* __restrict__ A,
                                                const float* __restrict__ B,
                                                const float* __restrict__ bias,
                                                const float* __restrict__ Cin,
                                                float* __restrict__ Cout,
                                                int M, int Nc, int K) {
    const int BM = 64, BN = 64, BK = 16;
    __shared__ float As[BK][BM + 4];
    __shared__ float Bs[BK][BN + 4];
    int bm0 = blockIdx.y * BM;
    int bn0 = blockIdx.x * BN;
    int tid = threadIdx.x;
    int tx = tid & 15, ty = tid >> 4;

    float acc[4][4] = {};

    int arow = tid >> 2;           // 0..63
    int acol4 = (tid & 3) * 4;     // 0,4,8,12
    int brow = tid >> 4;           // 0..15
    int bcol4 = (tid & 15) * 4;    // 0..60

    for (int k0 = 0; k0 < K; k0 += BK) {
        float4 av = make_float4(0.f, 0.f, 0.f, 0.f);
        int ar = bm0 + arow;
        if (ar < M) av = *(const float4*)(A + (size_t)ar * K + k0 + acol4);
        As[acol4 + 0][arow] = av.x;
        As[acol4 + 1][arow] = av.y;
        As[acol4 + 2][arow] = av.z;
        As[acol4 + 3][arow] = av.w;
        float4 bv = *(const float4*)(B + (size_t)(k0 + brow) * Nc + bn0 + bcol4);
        *(float4*)&Bs[brow][bcol4] = bv;
        __syncthreads();
#pragma unroll
        for (int k = 0; k < BK; k++) {
            float a[4], b[4];
#pragma unroll
            for (int i = 0; i < 4; i++) a[i] = As[k][ty * 4 + i];
#pragma unroll
            for (int j = 0; j < 4; j++) b[j] = Bs[k][tx * 4 + j];
#pragma unroll
            for (int i = 0; i < 4; i++)
#pragma unroll
                for (int j = 0; j < 4; j++) acc[i][j] += a[i] * b[j];
        }
        __syncthreads();
    }
#pragma unroll
    for (int i = 0; i < 4; i++) {
        int row = bm0 + ty * 4 + i;
        if (row >= M) continue;
#pragma unroll
        for (int j = 0; j < 4; j++) {
            int col = bn0 + tx * 4 + j;
            float v = acc[i][j];
            if (BIAS) v += bias[col];
            if (ADDC) v += Cin[(size_t)row * Nc + col];
            Cout[(size_t)row * Nc + col] = v;
        }
    }
}

// ---------------- LayerNorm(128) + leaky_relu + row L2 norm ----------------
__global__ __launch_bounds__(256) void ln_lrelu_norm(const float* __restrict__ X,
                                                     const float* __restrict__ g,
                                                     const float* __restrict__ b,
                                                     float* __restrict__ R,
                                                     float* __restrict__ rn, int Nn) {
    int wid = threadIdx.x >> 6, lane = threadIdx.x & 63;
    int node = blockIdx.x * 4 + wid;
    if (node >= Nn) return;
    const float* x = X + (size_t)node * 128;
    float v0 = x[lane], v1 = x[lane + 64];
    float mu = wave_sum(v0 + v1) * (1.f / 128.f);
    float d0 = v0 - mu, d1 = v1 - mu;
    float var = wave_sum(d0 * d0 + d1 * d1) * (1.f / 128.f);
    float rs = rsqrtf(var + 1e-5f);
    float r0 = d0 * rs * g[lane] + b[lane];
    float r1 = d1 * rs * g[lane + 64] + b[lane + 64];
    r0 = r0 > 0.f ? r0 : 0.01f * r0;
    r1 = r1 > 0.f ? r1 : 0.01f * r1;
    if (rn != nullptr) {
        float nrm = wave_sum(r0 * r0 + r1 * r1);
        if (lane == 0) rn[node] = sqrtf(nrm);
    }
    R[(size_t)node * 128 + lane] = r0;
    R[(size_t)node * 128 + lane + 64] = r1;
}

// ---------------- LayerNorm(256) + relu, in-place ----------------
__global__ __launch_bounds__(256) void ln_relu256(float* __restrict__ Z,
                                                  const float* __restrict__ g,
                                                  const float* __restrict__ b, int Nn) {
    int wid = threadIdx.x >> 6, lane = threadIdx.x & 63;
    int node = blockIdx.x * 4 + wid;
    if (node >= Nn) return;
    float* z = Z + (size_t)node * 256;
    float v[4];
#pragma unroll
    for (int q = 0; q < 4; q++) v[q] = z[lane + 64 * q];
    float mu = wave_sum(v[0] + v[1] + v[2] + v[3]) * (1.f / 256.f);
    float d[4], sq = 0.f;
#pragma unroll
    for (int q = 0; q < 4; q++) { d[q] = v[q] - mu; sq += d[q] * d[q]; }
    float var = wave_sum(sq) * (1.f / 256.f);
    float rs = rsqrtf(var + 1e-5f);
#pragma unroll
    for (int q = 0; q < 4; q++) {
        float y = d[q] * rs * g[lane + 64 * q] + b[lane + 64 * q];
        z[lane + 64 * q] = fmaxf(y, 0.f);
    }
}

// ---------------- per-node online-softmax aggregation + MessageNorm --------
__global__ __launch_bounds__(256) void aggregate_kernel(const float* __restrict__ R,
                                                        const int* __restrict__ offs,
                                                        const int* __restrict__ esrc,
                                                        const float* __restrict__ rn,
                                                        const float* __restrict__ tptr,
                                                        const float* __restrict__ scptr,
                                                        float* __restrict__ U, int Nn) {
    int wid = threadIdx.x >> 6, lane = threadIdx.x & 63;
    int node = blockIdx.x * 4 + wid;
    if (node >= Nn) return;
    float t = *tptr, sc = *scptr;
    int e0 = offs[node], e1 = offs[node + 1];
    float m0 = -INFINITY, m1 = -INFINITY;
    float s0 = 0.f, s1 = 0.f, w0 = 0.f, w1 = 0.f;
    for (int j = e0; j < e1; j++) {
        int sn = esrc[j];
        const float* rr = R + (size_t)sn * 128;
        float x0 = rr[lane], x1 = rr[lane + 64];
        float msg0 = fmaxf(x0, 0.f) + 1e-7f;
        float msg1 = fmaxf(x1, 0.f) + 1e-7f;
        float z0 = msg0 * t, z1 = msg1 * t;
        float nm0 = fmaxf(m0, z0), nm1 = fmaxf(m1, z1);
        float a0 = expf(m0 - nm0), a1 = expf(m1 - nm1);
        float p0 = expf(z0 - nm0), p1 = expf(z1 - nm1);
        s0 = s0 * a0 + p0;
        s1 = s1 * a1 + p1;
        w0 = w0 * a0 + msg0 * p0;
        w1 = w1 * a1 + msg1 * p1;
        m0 = nm0;
        m1 = nm1;
    }
    float agg0 = w0 / (s0 + 1e-16f);
    float agg1 = w1 / (s1 + 1e-16f);
    float nrm = sqrtf(wave_sum(agg0 * agg0 + agg1 * agg1));
    float fac = rn[node] * sc / fmaxf(nrm, 1e-12f);
    size_t base = (size_t)node * 128;
    U[base + lane] = R[base + lane] + agg0 * fac;
    U[base + lane + 64] = R[base + lane + 64] + agg1 * fac;
}

// ---------------- pooling ----------------
__global__ void pool_accum(const float* __restrict__ HF, const int* __restrict__ batch,
                           float* __restrict__ pool, float* __restrict__ cnt, int Nn) {
    int idx = blockIdx.x * blockDim.x + threadIdx.x;
    if (idx >= Nn * 128) return;
    int node = idx >> 7, f = idx & 127;
    int g = batch[node];
    atomicAdd(&pool[g * 128 + f], HF[idx]);
    if (f == 0) atomicAdd(&cnt[g], 1.0f);
}

__global__ void pool_div(const float* __restrict__ pool, const float* __restrict__ cnt,
                         float* __restrict__ out, int total) {
    int idx = blockIdx.x * blockDim.x + threadIdx.x;
    if (idx >= total) return;
    out[idx] = pool[idx] / fmaxf(cnt[idx >> 7], 1.0f);
}

// ---------------------------------------------------------------------------
extern "C" void kernel_launch(void* const* d_in, const int* in_sizes, int n_in,
                              void* d_out, int out_size, void* d_ws, size_t ws_size,
                              hipStream_t stream) {
    const float* x    = (const float*)d_in[0];
    const int*   ei   = (const int*)d_in[1];
    const int*   batch= (const int*)d_in[2];
    const float* encW = (const float*)d_in[3];
    const float* encB = (const float*)d_in[4];
    const float* ln_g = (const float*)d_in[5];
    const float* ln_b = (const float*)d_in[6];
    const float* tArr = (const float*)d_in[7];
    const float* scArr= (const float*)d_in[8];
    const float* W1   = (const float*)d_in[9];
    const float* b1   = (const float*)d_in[10];
    const float* mg   = (const float*)d_in[11];
    const float* mb   = (const float*)d_in[12];
    const float* W2   = (const float*)d_in[13];
    const float* b2   = (const float*)d_in[14];
    const float* fn_g = (const float*)d_in[15];
    const float* fn_b = (const float*)d_in[16];
    float* out = (float*)d_out;

    const int N = in_sizes[0] / 128;     // 10000
    const int E = in_sizes[1] / 2;       // 160000
    const int L = in_sizes[7];           // 14
    const int H = 128;

    const int* src = ei;
    const int* dst = ei + E;

    // workspace carve-out
    char* p = (char*)d_ws;
    auto alloc = [&](size_t bytes) -> void* {
        void* q = (void*)p;
        p += (bytes + 255) & ~(size_t)255;
        return q;
    };
    float* h    = (float*)alloc((size_t)N * H * 4);
    float* r    = (float*)alloc((size_t)N * H * 4);
    float* u    = (float*)alloc((size_t)N * H * 4);
    float* z1   = (float*)alloc((size_t)N * 2 * H * 4);
    float* rn   = (float*)alloc((size_t)N * 4);
    int*   deg  = (int*)alloc((size_t)N * 4);
    int*   offs = (int*)alloc((size_t)(N + 1) * 4);
    int*   curs = (int*)alloc((size_t)N * 4);
    int*   esrc = (int*)alloc((size_t)E * 4);
    float* pool = (float*)alloc(64 * 128 * 4);
    float* cnt  = (float*)alloc(64 * 4);

    // ---- CSR build (dst is an input -> rebuild every call) ----
    hipMemsetAsync(deg, 0, (size_t)N * 4, stream);
    hist_kernel<<<(E + 255) / 256, 256, 0, stream>>>(dst, deg, E);
    scan_kernel<<<1, 1024, 0, stream>>>(deg, offs, curs, N);
    scatter_kernel<<<(E + 255) / 256, 256, 0, stream>>>(src, dst, curs, esrc, E);

    const int nodeBlocks = (N + 3) / 4;

    // ---- encoder: h = x @ encW + encB ----
    {
        dim3 grid(H / 64, (N + 63) / 64);
        gemm_f32<true, false><<<grid, 256, 0, stream>>>(x, encW, encB, nullptr, h, N, H, H);
    }

    // ---- layers ----
    for (int i = 0; i < L; i++) {
        ln_lrelu_norm<<<nodeBlocks, 256, 0, stream>>>(h, ln_g + i * H, ln_b + i * H, r, rn, N);
        aggregate_kernel<<<nodeBlocks, 256, 0, stream>>>(r, offs, esrc, rn, tArr + i, scArr + i, u, N);
        {
            dim3 grid(2 * H / 64, (N + 63) / 64);
            gemm_f32<true, false><<<grid, 256, 0, stream>>>(u, W1 + (size_t)i * H * 2 * H,
                                                            b1 + (size_t)i * 2 * H, nullptr, z1,
                                                            N, 2 * H, H);
        }
        ln_relu256<<<nodeBlocks, 256, 0, stream>>>(z1, mg + (size_t)i * 2 * H, mb + (size_t)i * 2 * H, N);
        {
            dim3 grid(H / 64, (N + 63) / 64);
            gemm_f32<true, true><<<grid, 256, 0, stream>>>(z1, W2 + (size_t)i * 2 * H * H,
                                                           b2 + (size_t)i * H, h, h, N, H, 2 * H);
        }
    }

    // ---- final LN + leaky relu (into r) ----
    ln_lrelu_norm<<<nodeBlocks, 256, 0, stream>>>(h, fn_g, fn_b, r, nullptr, N);

    // ---- global mean pool ----
    hipMemsetAsync(pool, 0, 64 * 128 * 4, stream);
    hipMemsetAsync(cnt, 0, 64 * 4, stream);
    pool_accum<<<(N * 128 + 255) / 256, 256, 0, stream>>>(r, batch, pool, cnt, N);
    pool_div<<<(out_size + 255) / 256, 256, 0, stream>>>(pool, cnt, out, out_size);
}

// Round 2
// 1039.697 us; speedup vs baseline: 1.2702x; 1.2702x over previous
//
#include <hip/hip_runtime.h>
#include <cstdint>
#include <cstddef>

// ---------------------------------------------------------------------------
// DeeperGCN forward on MI355X. Round 2: bf16 MFMA GEMMs with fused LN
// epilogues, sorted-segment pooling, bf16 activations for the edge gather.
// N=10000 nodes, E=160000 edges, H=128, L=14 layers, G=64 graphs.
// ---------------------------------------------------------------------------

typedef __attribute__((ext_vector_type(8))) short bf16x8;
typedef __attribute__((ext_vector_type(4))) float f32x4;

__device__ inline float bf2f(ushort u) {
    union { uint i; float f; } v;
    v.i = (uint)u << 16;
    return v.f;
}
__device__ inline ushort f2bf(float f) {
    union { float f; uint i; } v;
    v.f = f;
    return (ushort)((v.i + 0x7fffu + ((v.i >> 16) & 1u)) >> 16);
}

__device__ inline float wave_sum(float v) {
#pragma unroll
    for (int off = 32; off > 0; off >>= 1) v += __shfl_xor(v, off, 64);
    return v;
}

// ---------------- CSR construction ----------------
__global__ void hist_kernel(const int* __restrict__ dst, int* __restrict__ deg, int E) {
    int e = blockIdx.x * blockDim.x + threadIdx.x;
    if (e < E) atomicAdd(&deg[dst[e]], 1);
}

__global__ __launch_bounds__(1024) void scan_kernel(const int* __restrict__ deg,
                                                    int* __restrict__ offs,
                                                    int* __restrict__ cursor, int N) {
    __shared__ int part[1024];
    int tid = threadIdx.x;
    int CH = (N + 1023) / 1024;
    int base = tid * CH;
    int s = 0;
    for (int i = 0; i < CH; i++) {
        int idx = base + i;
        if (idx < N) s += deg[idx];
    }
    part[tid] = s;
    __syncthreads();
    for (int off = 1; off < 1024; off <<= 1) {
        int v = (tid >= off) ? part[tid - off] : 0;
        __syncthreads();
        part[tid] += v;
        __syncthreads();
    }
    int run = (tid == 0) ? 0 : part[tid - 1];
    for (int i = 0; i < CH; i++) {
        int idx = base + i;
        if (idx < N) {
            offs[idx] = run;
            cursor[idx] = run;
            run += deg[idx];
        }
    }
    if (tid == 1023) offs[N] = part[1023];
}

__global__ void scatter_kernel(const int* __restrict__ src, const int* __restrict__ dst,
                               int* __restrict__ cursor, int* __restrict__ esrc, int E) {
    int e = blockIdx.x * blockDim.x + threadIdx.x;
    if (e < E) {
        int d = dst[e];
        int pos = atomicAdd(&cursor[d], 1);
        esrc[pos] = src[e];
    }
}

// ---------------- weight prep: fp32 [L][R][C] -> bf16 [L][C][R] ----------------
__global__ __launch_bounds__(256) void tconv_kernel(const float* __restrict__ in,
                                                    ushort* __restrict__ out, int Rr, int Cc) {
    __shared__ float tile[32][33];
    int lz = blockIdx.z;
    in += (size_t)lz * Rr * Cc;
    out += (size_t)lz * Rr * Cc;
    int c0 = blockIdx.x * 32, r0 = blockIdx.y * 32;
    int tx = threadIdx.x & 31, ty = threadIdx.x >> 5;  // ty 0..7
    for (int i = ty; i < 32; i += 8) tile[i][tx] = in[(size_t)(r0 + i) * Cc + c0 + tx];
    __syncthreads();
    for (int i = ty; i < 32; i += 8)
        out[(size_t)(c0 + i) * Rr + r0 + tx] = f2bf(tile[tx][i]);
}

__global__ void conv_kernel(const float* __restrict__ in, ushort* __restrict__ out, int n) {
    int i = blockIdx.x * blockDim.x + threadIdx.x;
    if (i < n) out[i] = f2bf(in[i]);
}

// ---------------- GEMM1: z1 = relu(LN(u @ W1 + b1; mg, mb)) --------------------
// A bf16 [M][128], Bt bf16 [256][128] -> Z bf16 [M][256]
__global__ __launch_bounds__(256) void gemm1_ln_relu(const ushort* __restrict__ A,
                                                     const ushort* __restrict__ Bt,
                                                     const float* __restrict__ bias,
                                                     const float* __restrict__ mg,
                                                     const float* __restrict__ mb,
                                                     ushort* __restrict__ Z, int M) {
    const int K = 128, BM = 32, BN = 256;
    __shared__ ushort As[BM][K + 8];
    __shared__ ushort Bs[BN][K + 8];
    __shared__ float partS[4][BM], partQ[4][BM];
    int tid = threadIdx.x, w = tid >> 6, l = tid & 63;
    int m0 = blockIdx.x * BM;
    const int CK = K / 8;
    for (int c = tid; c < BM * CK; c += 256) {
        int rr = c / CK, kc = c % CK;
        uint4 v = make_uint4(0, 0, 0, 0);
        if (m0 + rr < M) v = *(const uint4*)(A + (size_t)(m0 + rr) * K + kc * 8);
        *(uint4*)&As[rr][kc * 8] = v;
    }
    for (int c = tid; c < BN * CK; c += 256) {
        int rr = c / CK, kc = c % CK;
        *(uint4*)&Bs[rr][kc * 8] = *(const uint4*)(Bt + (size_t)rr * K + kc * 8);
    }
    __syncthreads();
    int q = l >> 4, ln = l & 15;
    f32x4 acc[2][4];
#pragma unroll
    for (int i = 0; i < 2; i++)
#pragma unroll
        for (int j = 0; j < 4; j++) acc[i][j] = (f32x4){0.f, 0.f, 0.f, 0.f};
#pragma unroll
    for (int ks = 0; ks < K; ks += 32) {
        bf16x8 a[2], b[4];
#pragma unroll
        for (int rt = 0; rt < 2; rt++) a[rt] = *(const bf16x8*)&As[rt * 16 + ln][ks + q * 8];
#pragma unroll
        for (int ct = 0; ct < 4; ct++)
            b[ct] = *(const bf16x8*)&Bs[w * 64 + ct * 16 + ln][ks + q * 8];
#pragma unroll
        for (int rt = 0; rt < 2; rt++)
#pragma unroll
            for (int ct = 0; ct < 4; ct++)
                acc[rt][ct] = __builtin_amdgcn_mfma_f32_16x16x32_bf16(a[rt], b[ct], acc[rt][ct], 0, 0, 0);
    }
    // epilogue: + bias, LN over 256, relu, store bf16
    float s1[2][4] = {}, s2[2][4] = {};
#pragma unroll
    for (int rt = 0; rt < 2; rt++)
#pragma unroll
        for (int ct = 0; ct < 4; ct++)
#pragma unroll
            for (int r = 0; r < 4; r++) {
                float v = acc[rt][ct][r] + bias[w * 64 + ct * 16 + ln];
                acc[rt][ct][r] = v;
                s1[rt][r] += v;
                s2[rt][r] += v * v;
            }
#pragma unroll
    for (int off = 1; off < 16; off <<= 1)
#pragma unroll
        for (int rt = 0; rt < 2; rt++)
#pragma unroll
            for (int r = 0; r < 4; r++) {
                s1[rt][r] += __shfl_xor(s1[rt][r], off, 64);
                s2[rt][r] += __shfl_xor(s2[rt][r], off, 64);
            }
    if (ln == 0)
#pragma unroll
        for (int rt = 0; rt < 2; rt++)
#pragma unroll
            for (int r = 0; r < 4; r++) {
                int row = rt * 16 + q * 4 + r;
                partS[w][row] = s1[rt][r];
                partQ[w][row] = s2[rt][r];
            }
    __syncthreads();
#pragma unroll
    for (int rt = 0; rt < 2; rt++)
#pragma unroll
        for (int r = 0; r < 4; r++) {
            int row = rt * 16 + q * 4 + r;
            float S = 0.f, Q = 0.f;
#pragma unroll
            for (int ww = 0; ww < 4; ww++) {
                S += partS[ww][row];
                Q += partQ[ww][row];
            }
            float mu = S * (1.f / 256.f);
            float var = Q * (1.f / 256.f) - mu * mu;
            float rs = rsqrtf(var + 1e-5f);
            int grow = m0 + row;
            if (grow < M) {
#pragma unroll
                for (int ct = 0; ct < 4; ct++) {
                    int col = w * 64 + ct * 16 + ln;
                    float y = (acc[rt][ct][r] - mu) * rs * mg[col] + mb[col];
                    y = fmaxf(y, 0.f);
                    Z[(size_t)grow * 256 + col] = f2bf(y);
                }
            }
        }
}

// ---------------- GEMM2: h' = h + (A @ W2 + b2); r = lrelu(LN(h')); rn = ||r|| --
// A bf16 [M][K], Bt bf16 [128][K]. RESID=false for the encoder (h' = A@W + b).
template <int K, bool RESID>
__global__ __launch_bounds__(256) void gemm2_ln_lrelu(const ushort* __restrict__ A,
                                                      const ushort* __restrict__ Bt,
                                                      const float* __restrict__ bias,
                                                      const float* __restrict__ lg,
                                                      const float* __restrict__ lb,
                                                      float* __restrict__ H,
                                                      ushort* __restrict__ R,
                                                      float* __restrict__ rn, int M) {
    const int BM = 32, BN = 128;
    __shared__ ushort As[BM][K + 8];
    __shared__ ushort Bs[BN][K + 8];
    __shared__ float partS[4][BM], partQ[4][BM];
    int tid = threadIdx.x, w = tid >> 6, l = tid & 63;
    int m0 = blockIdx.x * BM;
    const int CK = K / 8;
    for (int c = tid; c < BM * CK; c += 256) {
        int rr = c / CK, kc = c % CK;
        uint4 v = make_uint4(0, 0, 0, 0);
        if (m0 + rr < M) v = *(const uint4*)(A + (size_t)(m0 + rr) * K + kc * 8);
        *(uint4*)&As[rr][kc * 8] = v;
    }
    for (int c = tid; c < BN * CK; c += 256) {
        int rr = c / CK, kc = c % CK;
        *(uint4*)&Bs[rr][kc * 8] = *(const uint4*)(Bt + (size_t)rr * K + kc * 8);
    }
    __syncthreads();
    int q = l >> 4, ln = l & 15;
    f32x4 acc[2][2];
#pragma unroll
    for (int i = 0; i < 2; i++)
#pragma unroll
        for (int j = 0; j < 2; j++) acc[i][j] = (f32x4){0.f, 0.f, 0.f, 0.f};
#pragma unroll
    for (int ks = 0; ks < K; ks += 32) {
        bf16x8 a[2], b[2];
#pragma unroll
        for (int rt = 0; rt < 2; rt++) a[rt] = *(const bf16x8*)&As[rt * 16 + ln][ks + q * 8];
#pragma unroll
        for (int ct = 0; ct < 2; ct++)
            b[ct] = *(const bf16x8*)&Bs[w * 32 + ct * 16 + ln][ks + q * 8];
#pragma unroll
        for (int rt = 0; rt < 2; rt++)
#pragma unroll
            for (int ct = 0; ct < 2; ct++)
                acc[rt][ct] = __builtin_amdgcn_mfma_f32_16x16x32_bf16(a[rt], b[ct], acc[rt][ct], 0, 0, 0);
    }
    // epilogue: + bias (+ residual), write h fp32, LN over 128, lrelu -> r bf16, rn
    float s1[2][4] = {}, s2[2][4] = {};
#pragma unroll
    for (int rt = 0; rt < 2; rt++)
#pragma unroll
        for (int ct = 0; ct < 2; ct++)
#pragma unroll
            for (int r = 0; r < 4; r++) {
                int row = rt * 16 + q * 4 + r;
                int grow = m0 + row;
                int col = w * 32 + ct * 16 + ln;
                float v = acc[rt][ct][r] + bias[col];
                if (RESID && grow < M) v += H[(size_t)grow * 128 + col];
                if (grow < M) H[(size_t)grow * 128 + col] = v;
                acc[rt][ct][r] = v;
                s1[rt][r] += v;
                s2[rt][r] += v * v;
            }
#pragma unroll
    for (int off = 1; off < 16; off <<= 1)
#pragma unroll
        for (int rt = 0; rt < 2; rt++)
#pragma unroll
            for (int r = 0; r < 4; r++) {
                s1[rt][r] += __shfl_xor(s1[rt][r], off, 64);
                s2[rt][r] += __shfl_xor(s2[rt][r], off, 64);
            }
    if (ln == 0)
#pragma unroll
        for (int rt = 0; rt < 2; rt++)
#pragma unroll
            for (int r = 0; r < 4; r++) {
                int row = rt * 16 + q * 4 + r;
                partS[w][row] = s1[rt][r];
                partQ[w][row] = s2[rt][r];
            }
    __syncthreads();
    float yv[2][2][4];
    float t2[2][4] = {};
#pragma unroll
    for (int rt = 0; rt < 2; rt++)
#pragma unroll
        for (int r = 0; r < 4; r++) {
            int row = rt * 16 + q * 4 + r;
            float S = 0.f, Q = 0.f;
#pragma unroll
            for (int ww = 0; ww < 4; ww++) {
                S += partS[ww][row];
                Q += partQ[ww][row];
            }
            float mu = S * (1.f / 128.f);
            float var = Q * (1.f / 128.f) - mu * mu;
            float rs = rsqrtf(var + 1e-5f);
#pragma unroll
            for (int ct = 0; ct < 2; ct++) {
                int col = w * 32 + ct * 16 + ln;
                float y = (acc[rt][ct][r] - mu) * rs * lg[col] + lb[col];
                y = y > 0.f ? y : 0.01f * y;
                yv[rt][ct][r] = y;
                t2[rt][r] += y * y;
            }
        }
#pragma unroll
    for (int off = 1; off < 16; off <<= 1)
#pragma unroll
        for (int rt = 0; rt < 2; rt++)
#pragma unroll
            for (int r = 0; r < 4; r++) t2[rt][r] += __shfl_xor(t2[rt][r], off, 64);
    __syncthreads();
    if (ln == 0)
#pragma unroll
        for (int rt = 0; rt < 2; rt++)
#pragma unroll
            for (int r = 0; r < 4; r++) partS[w][rt * 16 + q * 4 + r] = t2[rt][r];
    __syncthreads();
#pragma unroll
    for (int rt = 0; rt < 2; rt++)
#pragma unroll
        for (int r = 0; r < 4; r++) {
            int row = rt * 16 + q * 4 + r;
            int grow = m0 + row;
            if (grow >= M) continue;
            float T = 0.f;
#pragma unroll
            for (int ww = 0; ww < 4; ww++) T += partS[ww][row];
            if (w == 0 && ln == 0) rn[grow] = sqrtf(T);
#pragma unroll
            for (int ct = 0; ct < 2; ct++) {
                int col = w * 32 + ct * 16 + ln;
                R[(size_t)grow * 128 + col] = f2bf(yv[rt][ct][r]);
            }
        }
}

// ---------------- per-node online-softmax aggregation + MessageNorm (bf16 io) --
__global__ __launch_bounds__(256) void aggregate_kernel(const ushort* __restrict__ R,
                                                        const int* __restrict__ offs,
                                                        const int* __restrict__ esrc,
                                                        const float* __restrict__ rn,
                                                        const float* __restrict__ tptr,
                                                        const float* __restrict__ scptr,
                                                        ushort* __restrict__ U, int Nn) {
    int wid = threadIdx.x >> 6, lane = threadIdx.x & 63;
    int node = blockIdx.x * 4 + wid;
    if (node >= Nn) return;
    float t = *tptr, sc = *scptr;
    int e0 = offs[node], e1 = offs[node + 1];
    float m0 = -INFINITY, m1 = -INFINITY;
    float s0 = 0.f, s1 = 0.f, w0 = 0.f, w1 = 0.f;
    for (int j = e0; j < e1; j++) {
        int sn = esrc[j];
        uint rv = *(const uint*)(R + (size_t)sn * 128 + 2 * lane);
        float x0 = bf2f((ushort)(rv & 0xffff));
        float x1 = bf2f((ushort)(rv >> 16));
        float msg0 = fmaxf(x0, 0.f) + 1e-7f;
        float msg1 = fmaxf(x1, 0.f) + 1e-7f;
        float z0 = msg0 * t, z1 = msg1 * t;
        float nm0 = fmaxf(m0, z0), nm1 = fmaxf(m1, z1);
        float a0 = __expf(m0 - nm0), a1 = __expf(m1 - nm1);
        float p0 = __expf(z0 - nm0), p1 = __expf(z1 - nm1);
        s0 = s0 * a0 + p0;
        s1 = s1 * a1 + p1;
        w0 = w0 * a0 + msg0 * p0;
        w1 = w1 * a1 + msg1 * p1;
        m0 = nm0;
        m1 = nm1;
    }
    float agg0 = w0 / (s0 + 1e-16f);
    float agg1 = w1 / (s1 + 1e-16f);
    float nrm = sqrtf(wave_sum(agg0 * agg0 + agg1 * agg1));
    float fac = rn[node] * sc / fmaxf(nrm, 1e-12f);
    uint ru = *(const uint*)(R + (size_t)node * 128 + 2 * lane);
    float r0 = bf2f((ushort)(ru & 0xffff));
    float r1 = bf2f((ushort)(ru >> 16));
    uint o = (uint)f2bf(r0 + agg0 * fac) | ((uint)f2bf(r1 + agg1 * fac) << 16);
    *(uint*)(U + (size_t)node * 128 + 2 * lane) = o;
}

// ---------------- pooling (batch sorted -> segment sums) ----------------
__global__ void boundaries_kernel(const int* __restrict__ batch, int* __restrict__ gstart,
                                  int N, int G) {
    int n = blockIdx.x * blockDim.x + threadIdx.x;
    if (n >= N) return;
    int b = batch[n];
    if (n == 0)
        for (int g = 0; g <= b; g++) gstart[g] = 0;
    else {
        int pb = batch[n - 1];
        for (int g = pb + 1; g <= b; g++) gstart[g] = n;
    }
    if (n == N - 1)
        for (int g = b + 1; g <= G; g++) gstart[g] = N;
}

__global__ __launch_bounds__(128) void pool_kernel(const ushort* __restrict__ R,
                                                   const int* __restrict__ gstart,
                                                   float* __restrict__ out) {
    int g = blockIdx.x, f = threadIdx.x;
    int s = gstart[g], e = gstart[g + 1];
    float acc = 0.f;
    for (int n = s; n < e; n++) acc += bf2f(R[(size_t)n * 128 + f]);
    out[g * 128 + f] = acc / fmaxf((float)(e - s), 1.f);
}

// ---------------------------------------------------------------------------
extern "C" void kernel_launch(void* const* d_in, const int* in_sizes, int n_in,
                              void* d_out, int out_size, void* d_ws, size_t ws_size,
                              hipStream_t stream) {
    const float* x     = (const float*)d_in[0];
    const int*   ei    = (const int*)d_in[1];
    const int*   batch = (const int*)d_in[2];
    const float* encW  = (const float*)d_in[3];
    const float* encB  = (const float*)d_in[4];
    const float* ln_g  = (const float*)d_in[5];
    const float* ln_b  = (const float*)d_in[6];
    const float* tArr  = (const float*)d_in[7];
    const float* scArr = (const float*)d_in[8];
    const float* W1    = (const float*)d_in[9];
    const float* b1    = (const float*)d_in[10];
    const float* mg    = (const float*)d_in[11];
    const float* mb    = (const float*)d_in[12];
    const float* W2    = (const float*)d_in[13];
    const float* b2    = (const float*)d_in[14];
    const float* fn_g  = (const float*)d_in[15];
    const float* fn_b  = (const float*)d_in[16];
    float* out = (float*)d_out;

    const int N = in_sizes[0] / 128;  // 10000
    const int E = in_sizes[1] / 2;    // 160000
    const int L = in_sizes[7];        // 14
    const int H = 128;
    const int G = 64;

    const int* src = ei;
    const int* dst = ei + E;

    char* p = (char*)d_ws;
    auto alloc = [&](size_t bytes) -> void* {
        void* q = (void*)p;
        p += (bytes + 255) & ~(size_t)255;
        return q;
    };
    float*  h     = (float*)alloc((size_t)N * H * 4);
    ushort* r     = (ushort*)alloc((size_t)N * H * 2);
    ushort* u     = (ushort*)alloc((size_t)N * H * 2);
    ushort* z1    = (ushort*)alloc((size_t)N * 2 * H * 2);
    ushort* xb    = (ushort*)alloc((size_t)N * H * 2);
    float*  rn    = (float*)alloc((size_t)N * 4);
    ushort* W1t   = (ushort*)alloc((size_t)L * H * 2 * H * 2);
    ushort* W2t   = (ushort*)alloc((size_t)L * H * 2 * H * 2);
    ushort* encWt = (ushort*)alloc((size_t)H * H * 2);
    int*    deg   = (int*)alloc((size_t)N * 4);
    int*    offs  = (int*)alloc((size_t)(N + 1) * 4);
    int*    curs  = (int*)alloc((size_t)N * 4);
    int*    esrc  = (int*)alloc((size_t)E * 4);
    int*    gstart= (int*)alloc((size_t)(G + 1) * 4);

    // ---- CSR build ----
    hipMemsetAsync(deg, 0, (size_t)N * 4, stream);
    hist_kernel<<<(E + 255) / 256, 256, 0, stream>>>(dst, deg, E);
    scan_kernel<<<1, 1024, 0, stream>>>(deg, offs, curs, N);
    scatter_kernel<<<(E + 255) / 256, 256, 0, stream>>>(src, dst, curs, esrc, E);

    // ---- weight prep ----
    {
        dim3 g1(2 * H / 32, H / 32, L);       // W1 [L][128][256] -> W1t [L][256][128]
        tconv_kernel<<<g1, 256, 0, stream>>>(W1, W1t, H, 2 * H);
        dim3 g2(H / 32, 2 * H / 32, L);       // W2 [L][256][128] -> W2t [L][128][256]
        tconv_kernel<<<g2, 256, 0, stream>>>(W2, W2t, 2 * H, H);
        dim3 g3(H / 32, H / 32, 1);           // encW [128][128] -> encWt [128][128]
        tconv_kernel<<<g3, 256, 0, stream>>>(encW, encWt, H, H);
        conv_kernel<<<(N * H + 255) / 256, 256, 0, stream>>>(x, xb, N * H);
    }

    const int MB = (N + 31) / 32;   // 313 GEMM row-blocks
    const int nodeBlocks = (N + 3) / 4;

    // ---- encoder GEMM + LN0 + lrelu ----
    gemm2_ln_lrelu<128, false><<<MB, 256, 0, stream>>>(xb, encWt, encB, ln_g, ln_b,
                                                       h, r, rn, N);

    // ---- layers ----
    for (int i = 0; i < L; i++) {
        aggregate_kernel<<<nodeBlocks, 256, 0, stream>>>(r, offs, esrc, rn,
                                                         tArr + i, scArr + i, u, N);
        gemm1_ln_relu<<<MB, 256, 0, stream>>>(u, W1t + (size_t)i * H * 2 * H,
                                              b1 + (size_t)i * 2 * H,
                                              mg + (size_t)i * 2 * H,
                                              mb + (size_t)i * 2 * H, z1, N);
        const float* ng = (i < L - 1) ? (ln_g + (size_t)(i + 1) * H) : fn_g;
        const float* nb = (i < L - 1) ? (ln_b + (size_t)(i + 1) * H) : fn_b;
        gemm2_ln_lrelu<256, true><<<MB, 256, 0, stream>>>(z1, W2t + (size_t)i * H * 2 * H,
                                                          b2 + (size_t)i * H, ng, nb,
                                                          h, r, rn, N);
    }

    // ---- pooling ----
    boundaries_kernel<<<(N + 255) / 256, 256, 0, stream>>>(batch, gstart, N, G);
    pool_kernel<<<G, 128, 0, stream>>>(r, gstart, out);
}